// Round 2
// baseline (467.024 us; speedup 1.0000x reference)
//
#include <hip/hip_runtime.h>
#include <stdint.h>

// out[m,n] = sum_k x[m,k]*W[n,k] + sum_r y[m,r]*A[n,r],  y = x @ B^T
// M=256, N=8192, K=8192, R=16. fp32 in/out; bf16 MFMA compute (thr 0.18).

#define DM 256
#define DK 8192
#define DN 8192
#define RLORA 16

#define TN 128                  // n-cols per block
#define BK 64                   // k per iteration
#define KSPLIT 8
#define KCHUNK (DK / KSPLIT)    // 1024
#define NITER (KCHUNK / BK)     // 16

typedef short bf16x8 __attribute__((ext_vector_type(8)));   // 4 VGPRs
typedef float f32x4v __attribute__((ext_vector_type(4)));

typedef __attribute__((address_space(1))) const unsigned char glbc_u8;
typedef __attribute__((address_space(3))) unsigned char lds_u8;

__device__ __forceinline__ unsigned short f2bf(float f) {
  unsigned u = __builtin_bit_cast(unsigned, f);
  u += 0x7FFFu + ((u >> 16) & 1u);           // RNE
  return (unsigned short)(u >> 16);
}

__device__ __forceinline__ bf16x8 pack8(float4 a, float4 b) {
  bf16x8 r;
  r[0] = (short)f2bf(a.x); r[1] = (short)f2bf(a.y);
  r[2] = (short)f2bf(a.z); r[3] = (short)f2bf(a.w);
  r[4] = (short)f2bf(b.x); r[5] = (short)f2bf(b.y);
  r[6] = (short)f2bf(b.z); r[7] = (short)f2bf(b.w);
  return r;
}

// ---------------------------------------------------------------------------
// Prep: x -> bf16 (xb), and partial y = x @ B^T accumulated into y32 (fp32).
// grid (8 k-slices, 64 m-groups of 4 rows) = 512 blocks; B traffic 32 MB.
__global__ __launch_bounds__(256) void prep_x(
    const float* __restrict__ x, const float* __restrict__ Bm,
    unsigned short* __restrict__ xb, float* __restrict__ y32) {
  const int ks = blockIdx.x;            // k-slice of 1024
  const int m0 = blockIdx.y * 4;
  const int t = threadIdx.x;
  const int k0 = ks * 1024 + t * 4;
  float4 xv[4];
#pragma unroll
  for (int i = 0; i < 4; ++i) {
    xv[i] = *(const float4*)(x + (size_t)(m0 + i) * DK + k0);
    ushort4 h;
    h.x = f2bf(xv[i].x); h.y = f2bf(xv[i].y);
    h.z = f2bf(xv[i].z); h.w = f2bf(xv[i].w);
    *(ushort4*)(xb + (size_t)(m0 + i) * DK + k0) = h;
  }
  float acc[4][RLORA];
#pragma unroll
  for (int r = 0; r < RLORA; ++r) {
    float4 b = *(const float4*)(Bm + (size_t)r * DK + k0);
#pragma unroll
    for (int i = 0; i < 4; ++i)
      acc[i][r] = xv[i].x * b.x + xv[i].y * b.y + xv[i].z * b.z + xv[i].w * b.w;
  }
#pragma unroll
  for (int off = 32; off >= 1; off >>= 1)
#pragma unroll
    for (int i = 0; i < 4; ++i)
#pragma unroll
      for (int r = 0; r < RLORA; ++r)
        acc[i][r] += __shfl_xor(acc[i][r], off, 64);
  __shared__ float red[4][4][RLORA];
  const int lane = t & 63, wv = t >> 6;
  if (lane == 0) {
#pragma unroll
    for (int i = 0; i < 4; ++i)
#pragma unroll
      for (int r = 0; r < RLORA; ++r) red[wv][i][r] = acc[i][r];
  }
  __syncthreads();
  if (t < 64) {
    int i = t >> 4, r = t & 15;
    float s = red[0][i][r] + red[1][i][r] + red[2][i][r] + red[3][i][r];
    atomicAdd(y32 + (m0 + i) * RLORA + r, s);
  }
}

// y32 fp32 [256][16] -> yb bf16 [256][64] zero-padded.  grid 64 x 256.
__global__ __launch_bounds__(256) void pack_y(
    const float* __restrict__ y32, unsigned short* __restrict__ yb) {
  int e = blockIdx.x * 256 + threadIdx.x;    // 0..16383
  int m = e >> 6, c = e & 63;
  yb[e] = (c < RLORA) ? f2bf(y32[m * RLORA + c]) : (unsigned short)0;
}

// ---------------------------------------------------------------------------
// Main GEMM: block 256(m) x 128(n), 512 thr = 8 waves (1m x 8n, wave 256x16).
// x: double-buffered LDS via global_load_lds (frag-linear layout).
// W: global fp32 -> VGPR -> in-reg bf16 pack -> MFMA B-operand (no LDS).
// Split-K=8: partial tiles to ws (+reduce kernel), or atomicAdd fallback.
__global__ __launch_bounds__(512, 4) void lora_gemm(
    const unsigned short* __restrict__ xb,   // [256][8192] bf16
    const float* __restrict__ W,             // [8192][8192] fp32
    const unsigned short* __restrict__ yb,   // [256][64] bf16 padded
    const float* __restrict__ A,             // [8192][16] fp32
    float* __restrict__ out,                 // [256][8192] fp32 (zeroed)
    float* __restrict__ part) {              // [KSPLIT][256][8192] or null
  __shared__ unsigned short xs[2][DM * BK];  // 2 x 32 KB

  const int tid = threadIdx.x;
  const int lane = tid & 63;
  const int wave = tid >> 6;                 // 0..7 = n-slice
  const int nb = blockIdx.x * TN;
  const int kz = blockIdx.y;
  const int kb = kz * KCHUNK;
  const int n0 = nb + wave * 16;
  const int qr = lane & 15;
  const int quad = lane >> 4;

  // x staging: 4 global_load_lds per wave per iter; frag-linear chunk layout:
  // chunk idx = ((g*2+s)*4+c)*16+r  (g=m-group, s=k-half, c=k-octet, r=row)
  const unsigned short* xgp[4];
  unsigned xdst[4];
#pragma unroll
  for (int j = 0; j < 4; ++j) {
    int idx = (wave * 4 + j) * 64 + lane;
    int r = idx & 15, c = (idx >> 4) & 3, s = (idx >> 6) & 1, g = idx >> 7;
    xgp[j] = xb + (size_t)(g * 16 + r) * DK + kb + s * 32 + c * 8;
    xdst[j] = (unsigned)((wave * 4 + j) * 1024);
  }
  // W in-reg: lane holds W[n0+qr][kb + quad*8 ..] (8 floats per s-half)
  const float* wp = W + (size_t)(n0 + qr) * DK + kb + quad * 8;

  f32x4v acc[16];
#pragma unroll
  for (int g = 0; g < 16; ++g) acc[g] = (f32x4v){0.f, 0.f, 0.f, 0.f};

  const bool isLora = (kz == 0);
  const int niter = isLora ? NITER + 1 : NITER;

  // prologue: W(0) -> regs, x(0) -> xs[0]
  float4 f0 = *(const float4*)(wp);
  float4 f1 = *(const float4*)(wp + 4);
  float4 f2 = *(const float4*)(wp + 32);
  float4 f3 = *(const float4*)(wp + 36);
  wp += BK;
#pragma unroll
  for (int j = 0; j < 4; ++j) {
    __builtin_amdgcn_global_load_lds((glbc_u8*)xgp[j],
        (lds_u8*)((char*)&xs[0][0] + xdst[j]), 16, 0, 0);
    xgp[j] += BK;
  }
  __syncthreads();

  for (int it = 0; it < niter; ++it) {
    const int cur = it & 1, nxt = (it + 1) & 1;
    const int ni = it + 1;
    // stage next x tile (other buffer: safe before barrier)
    if (ni < NITER) {
#pragma unroll
      for (int j = 0; j < 4; ++j) {
        __builtin_amdgcn_global_load_lds((glbc_u8*)xgp[j],
            (lds_u8*)((char*)&xs[nxt][0] + xdst[j]), 16, 0, 0);
        xgp[j] += BK;
      }
    } else if (ni == NITER && isLora) {
#pragma unroll
      for (int j = 0; j < 4; ++j) {
        int idx = (wave * 4 + j) * 64 + lane;
        int r = idx & 15, c = (idx >> 4) & 3, s = (idx >> 6) & 1, g = idx >> 7;
        const unsigned short* gp = yb + (g * 16 + r) * 64 + s * 32 + c * 8;
        __builtin_amdgcn_global_load_lds((glbc_u8*)gp,
            (lds_u8*)((char*)&xs[nxt][0] + xdst[j]), 16, 0, 0);
      }
    }
    // convert current W regs -> b-frags (B[n=lane&15][k=quad*8+j])
    bf16x8 b0 = pack8(f0, f1);
    bf16x8 b1 = pack8(f2, f3);
    // prefetch next W / A into the freed regs
    if (ni < NITER) {
      f0 = *(const float4*)(wp);
      f1 = *(const float4*)(wp + 4);
      f2 = *(const float4*)(wp + 32);
      f3 = *(const float4*)(wp + 36);
      wp += BK;
    } else if (ni == NITER && isLora) {
      const float* ap = A + (size_t)(n0 + qr) * RLORA + quad * 8;
      float4 z = {0.f, 0.f, 0.f, 0.f};
      f0 = (quad < 2) ? *(const float4*)(ap) : z;
      f1 = (quad < 2) ? *(const float4*)(ap + 4) : z;
      f2 = z; f3 = z;
    }
    // compute: 32 MFMA, a-frags streamed from LDS (conflict-free linear)
    const char* xbase = (const char*)&xs[cur][0];
#pragma unroll
    for (int g = 0; g < 16; ++g) {
      bf16x8 a = *(const bf16x8*)(xbase + ((g * 2 + 0) * 64 + lane) * 16);
      acc[g] = __builtin_amdgcn_mfma_f32_16x16x32_bf16(a, b0, acc[g], 0, 0, 0);
    }
#pragma unroll
    for (int g = 0; g < 16; ++g) {
      bf16x8 a = *(const bf16x8*)(xbase + ((g * 2 + 1) * 64 + lane) * 16);
      acc[g] = __builtin_amdgcn_mfma_f32_16x16x32_bf16(a, b1, acc[g], 0, 0, 0);
    }
    __syncthreads();
  }

  // epilogue: C/D layout col=lane&15, row=quad*4+rg  [m89-verified]
  if (part) {
    float* pb = part + (size_t)kz * DM * DN + n0 + (lane & 15);
#pragma unroll
    for (int g = 0; g < 16; ++g)
#pragma unroll
      for (int rg = 0; rg < 4; ++rg)
        pb[(size_t)(g * 16 + quad * 4 + rg) * DN] = acc[g][rg];
  } else {
    float* ob = out + n0 + (lane & 15);
#pragma unroll
    for (int g = 0; g < 16; ++g)
#pragma unroll
      for (int rg = 0; rg < 4; ++rg)
        atomicAdd(ob + (size_t)(g * 16 + quad * 4 + rg) * DN, acc[g][rg]);
  }
}

// out = sum_kz part[kz]  (fully overwrites out).  grid 2048 x 256.
__global__ __launch_bounds__(256) void reduce_k(
    const float* __restrict__ part, float* __restrict__ out) {
  size_t i = ((size_t)blockIdx.x * 256 + threadIdx.x) * 4;
  float4 s = *(const float4*)(part + i);
#pragma unroll
  for (int kz = 1; kz < KSPLIT; ++kz) {
    float4 v = *(const float4*)(part + (size_t)kz * DM * DN + i);
    s.x += v.x; s.y += v.y; s.z += v.z; s.w += v.w;
  }
  *(float4*)(out + i) = s;
}

// ---------------------------------------------------------------------------
extern "C" void kernel_launch(void* const* d_in, const int* in_sizes, int n_in,
                              void* d_out, int out_size, void* d_ws, size_t ws_size,
                              hipStream_t stream) {
  const float* x  = (const float*)d_in[0];   // [4,64,8192]
  const float* W  = (const float*)d_in[1];   // [8192,8192]
  const float* A  = (const float*)d_in[2];   // [8192,16]
  const float* Bm = (const float*)d_in[3];   // [16,8192]
  float* out = (float*)d_out;

  unsigned short* xb = (unsigned short*)d_ws;            // 4 MiB
  unsigned short* yb = xb + (size_t)DM * DK;             // 32 KiB
  float* y32 = (float*)(yb + (size_t)DM * 64);           // 16 KiB
  size_t base_bytes = (size_t)DM * DK * 2 + (size_t)DM * 64 * 2 +
                      (size_t)DM * RLORA * 4;            // 4,243,456 (16B-mult)
  size_t part_bytes = (size_t)KSPLIT * DM * DN * 4;      // 64 MiB
  bool use_part = ws_size >= base_bytes + part_bytes;
  float* part = use_part ? (float*)((char*)d_ws + base_bytes) : nullptr;

  hipMemsetAsync(d_out, 0, (size_t)out_size * sizeof(float), stream);
  hipMemsetAsync(y32, 0, (size_t)DM * RLORA * sizeof(float), stream);
  prep_x<<<dim3(8, 64), 256, 0, stream>>>(x, Bm, xb, y32);
  pack_y<<<64, 256, 0, stream>>>(y32, yb);
  lora_gemm<<<dim3(DN / TN, KSPLIT), 512, 0, stream>>>(xb, W, yb, A, out, part);
  if (use_part) reduce_k<<<2048, 256, 0, stream>>>(part, out);
}